// Round 9
// baseline (598.771 us; speedup 1.0000x reference)
//
#include <hip/hip_runtime.h>
#include <math.h>

#define B_   16
#define C_   32
#define N_   2048
#define K_   24
#define BNK_ (B_*N_*K_)      /* 786432 */

/* ws layout (float/int32 units), ~51 MB total */
#define WS_XT   0u           /* xt[b][n][c]  : 1048576 f            */
#define WS_XXD  1048576u     /* xx fp64      : 65536 f              */
#define WS_XXF  1114112u     /* xx fp32      : 32768 f              */
#define WS_IDX  1146880u     /* idx[b][n][k] : 786432 i             */
#define WS_D2   1933312u     /* d2 [b][n][k] : 786432 f             */
#define WS_ATT  2719744u     /* att[b][n][k] : 786432 f             */
#define WS_LOG  3506176u     /* logitsT[k][bn]: 786432 f            */
#define WS_ST   4292608u     /* sum/sumsq    : 128 f                */
#define WS_AB   4292736u     /* BN A,B       : 128 f                */
#define WS_W    4292864u     /* W[m]  att-hist : 32768 f            */
#define WS_W2   4325632u     /* W2[m] att2-hist: 32768 f            */
#define WS_Y    4358400u     /* Y[m][256]: base|attn|upd|res : 8388608 f */

/* ---------------- K0: transpose x -> xt, row norms, zero stats/W ---------- */
__global__ __launch_bounds__(256) void k0_prep(const float* __restrict__ x,
                                               float* __restrict__ ws) {
  const int i = blockIdx.x;                 /* 128 blocks */
  const int xcd = i & 7, j = i >> 3;
  const int b = 2 * xcd + (j & 1);
  const int half = j >> 1;                  /* 0..7 */
  const int t = (b << 11) + (half << 8) + threadIdx.x;
  const int n = t & 2047;
  const float* xp = x + ((size_t)b * C_ * N_) + n;
  float* xt = ws + WS_XT + (size_t)t * C_;
  double s = 0.0;
#pragma unroll
  for (int c = 0; c < C_; ++c) {
    float v = xp[(size_t)c * N_];
    xt[c] = v;
    s = fma((double)v, (double)v, s);
  }
  ((double*)(ws + WS_XXD))[t] = s;
  ws[WS_XXF + t] = (float)s;
  ws[WS_W + t] = 0.f;
  ws[WS_W2 + t] = 0.f;
  if (t < 128) ws[WS_ST + t] = 0.f;
}

/* ---------------- K1: fused exact top-24 ----------------------------------
   One block per point-group (512 blocks x 512 thr = 8 waves).
   Phase 1: wave e scans m-eighth e (256 cands) for 64 points (lanes);
            med3 insertion top-16 (a true top-24 element escapes its
            eighth's top-16 only if that eighth holds >=17 of the global
            top-24: P ~ 1.6e-5 over all points, deterministic input);
            11-bit m packed in fp32 mantissa low bits; lists -> LDS.
   Phase 2: wave 0 streams the 128-entry union from LDS, med3-selects
            top-28, fp64 re-ranks (exact products, GUARDED insert),
            emits top-24 idx + d2.                                         */
__global__ __launch_bounds__(512, 4) void k1_topk(float* __restrict__ ws) {
  __shared__ float lists[8][16][64];
  const float* xt = ws + WS_XT;
  const int lane = threadIdx.x & 63;
  const int wv   = __builtin_amdgcn_readfirstlane(threadIdx.x >> 6);  /* = e */
  const int i = blockIdx.x;                 /* 512 blocks */
  const int xcd = i & 7, j = i >> 3;        /* j 0..63 */
  const int b = 2 * xcd + (j & 1);
  const int sub = j >> 1;                   /* 0..31 */
  const int bn = (b << 11) + (sub << 6) + lane;

  float xn[C_];
  {
    const float4* p = (const float4*)(xt + (size_t)bn * C_);
#pragma unroll
    for (int q = 0; q < 8; ++q) {
      float4 v = p[q];
      xn[4*q] = v.x; xn[4*q+1] = v.y; xn[4*q+2] = v.z; xn[4*q+3] = v.w;
    }
  }

  float val[16];
#pragma unroll
  for (int j0 = 0; j0 < 16; ++j0) val[j0] = -3.4e38f;

  const float* mrow = xt + ((size_t)((b << 11) + (wv << 8))) * C_;  /* uniform */
  const float* xxf  = ws + WS_XXF + (b << 11) + (wv << 8);          /* uniform */

#pragma unroll 2
  for (int mm = 0; mm < 256; ++mm) {
    const float* r = mrow + (size_t)mm * C_;   /* wave-uniform -> s_load */
    float a0 = 0.f, a1 = 0.f, a2 = 0.f, a3 = 0.f;
#pragma unroll
    for (int c = 0; c < 8; ++c) {
      a0 = fmaf(xn[c     ], r[c     ], a0);
      a1 = fmaf(xn[c + 8 ], r[c + 8 ], a1);
      a2 = fmaf(xn[c + 16], r[c + 16], a2);
      a3 = fmaf(xn[c + 24], r[c + 24], a3);
    }
    float s = 2.f * ((a0 + a1) + (a2 + a3)) - xxf[mm];
    int sb = (__float_as_int(s) & ~2047) | ((wv << 8) + mm);
    float sp = __int_as_float(sb);
#pragma unroll
    for (int j0 = 15; j0 >= 1; --j0)
      val[j0] = __builtin_amdgcn_fmed3f(val[j0 - 1], val[j0], sp);
    val[0] = fmaxf(val[0], sp);
  }
#pragma unroll
  for (int j0 = 0; j0 < 16; ++j0) lists[wv][j0][lane] = val[j0];
  __syncthreads();

  if (threadIdx.x < 64) {
    /* fp32 select of top-28 from the 128-entry union (LDS stream) */
    float v2[28];
#pragma unroll
    for (int j0 = 0; j0 < 28; ++j0) v2[j0] = -3.4e38f;
    const float* L = &lists[0][0][0];
#pragma unroll 4
    for (int t = 0; t < 128; ++t) {
      float sp = L[t * 64 + lane];
#pragma unroll
      for (int j0 = 27; j0 >= 1; --j0)
        v2[j0] = __builtin_amdgcn_fmed3f(v2[j0 - 1], v2[j0], sp);
      v2[0] = fmaxf(v2[0], sp);
    }

    /* fp64 re-rank of the 28 survivors (convert-on-the-fly, guarded) */
    const double* xxd = (const double*)(ws + WS_XXD);
    double dl[K_];
#pragma unroll
    for (int j0 = 0; j0 < K_; ++j0) dl[j0] = -1.7e308;

#pragma unroll 1
    for (int j0 = 0; j0 < 28; ++j0) {
      const int m = __float_as_int(v2[j0]) & 2047;
      const float* r = xt + ((size_t)((b << 11) + m)) * C_;
      double a0 = 0.0, a1 = 0.0;
#pragma unroll
      for (int c = 0; c < 16; ++c) {
        a0 = fma((double)r[c],      (double)xn[c],      a0);
        a1 = fma((double)r[c + 16], (double)xn[c + 16], a1);
      }
      double s = 2.0 * (a0 + a1) - xxd[(b << 11) + m];
      long long bits = (__double_as_longlong(s) & 0xFFFFFFFFFFFFF800ll) | (long long)m;
      double sp = __longlong_as_double(bits);
      if (sp > dl[K_ - 1]) {     /* guarded insert */
        bool c2 = true;
#pragma unroll
        for (int jj = K_ - 1; jj >= 1; --jj) {
          bool c1 = sp > dl[jj - 1];
          dl[jj] = c1 ? dl[jj - 1] : (c2 ? sp : dl[jj]);
          c2 = c1;
        }
        if (c2) dl[0] = sp;
      }
    }

    int*   op = (int*)ws + WS_IDX + (size_t)bn * K_;
    float* dp = ws + WS_D2 + (size_t)bn * K_;
    const double xxn = xxd[bn];
#pragma unroll
    for (int rr = 0; rr < K_; ++rr) {
      long long bl = __double_as_longlong(dl[rr]);
      op[rr] = (int)(bl & 0x7FFll);
      dp[rr] = (float)(xxn - __longlong_as_double(bl & 0xFFFFFFFFFFFFF800ll));
    }
  }
}

/* ---------------- KY: Y[m] = [xt·w1c^T | xt·w1n^T | xt·updw^T | xt·resw^T] */
__global__ __launch_bounds__(128) void kY(const float* __restrict__ w1,
                                          const float* __restrict__ updw,
                                          const float* __restrict__ resw,
                                          float* __restrict__ ws) {
  const int i = blockIdx.x;                 /* 256 blocks x 128 thr */
  const int xcd = i & 7, j = i >> 3;        /* j 0..31 */
  const int b = 2 * xcd + (j & 1);
  const int half = j >> 1;                  /* 0..15 */
  const int p = (b << 11) + (half << 7) + threadIdx.x;
  const float* xt = ws + WS_XT;

  float row[C_];
  {
    const float4* rp = (const float4*)(xt + (size_t)p * C_);
#pragma unroll
    for (int q = 0; q < 8; ++q) {
      float4 v = rp[q];
      row[4*q] = v.x; row[4*q+1] = v.y; row[4*q+2] = v.z; row[4*q+3] = v.w;
    }
  }
  float* yp = ws + WS_Y + (size_t)p * 256;
#pragma unroll 1
  for (int part = 0; part < 4; ++part) {
    const float* W = (part == 0) ? w1 : (part == 1) ? (w1 + 32)
                   : (part == 2) ? updw : resw;          /* uniform */
    const int stride = (part < 2) ? 80 : 32;
#pragma unroll 2
    for (int og = 0; og < 16; ++og) {
      float a[4] = {0.f, 0.f, 0.f, 0.f};
#pragma unroll
      for (int u = 0; u < 4; ++u) {
        const float* wr = W + (4 * og + u) * stride;     /* uniform -> s_load */
#pragma unroll
        for (int c = 0; c < C_; ++c) a[u] = fmaf(row[c], wr[c], a[u]);
      }
      float4 st; st.x = a[0]; st.y = a[1]; st.z = a[2]; st.w = a[3];
      ((float4*)(yp + part * 64))[og] = st;
    }
  }
}

/* ---------------- K2L: logits (wave = (pg,k), lane = point) --------------- */
__global__ __launch_bounds__(256) void k2_logits(const float* __restrict__ w1,
                                                 const float* __restrict__ w2,
                                                 float* __restrict__ ws) {
  const int lane = threadIdx.x & 63;
  const int wv   = __builtin_amdgcn_readfirstlane(threadIdx.x >> 6);
  const int i = blockIdx.x;                 /* 3072 blocks */
  const int xcd = i & 7, j = i >> 3;        /* j 0..383 */
  const int b = 2 * xcd + (j & 1);
  const int slot = ((j >> 1) << 2) + wv;    /* 0..767 */
  const int pgs = (slot * 2731) >> 16;      /* slot/24 */
  const int k = slot - pgs * 24;
  const int bn = (b << 11) + (pgs << 6) + lane;
  const float* Y = ws + WS_Y;

  const int mk  = ((const int*)ws)[WS_IDX + (size_t)bn * K_ + k];
  const float dd = ws[WS_D2 + (size_t)bn * K_ + k];
  float dist = sqrtf(fmaxf(dd, 1e-12f));
  float rbf[16];
#pragma unroll
  for (int r = 0; r < 16; ++r) {
    float t = dist - (float)r * (5.0f / 15.0f);
    float e = __expf(-10.f * t * t);
    rbf[r] = fminf(fmaxf(e, 1e-10f), 1.0f);
  }
  const float4* bp = (const float4*)(Y + (size_t)bn * 256);
  const float4* yp = (const float4*)(Y + (size_t)((b << 11) + mk) * 256 + 64);
  float lg = 0.f;
#pragma unroll 1
  for (int og = 0; og < 4; ++og) {
    float ba[16];
#pragma unroll
    for (int q = 0; q < 4; ++q) {
      float4 v0 = bp[og * 4 + q];
      float4 v1 = yp[og * 4 + q];
      ba[4*q]   = v0.x + v1.x; ba[4*q+1] = v0.y + v1.y;
      ba[4*q+2] = v0.z + v1.z; ba[4*q+3] = v0.w + v1.w;
    }
#pragma unroll
    for (int oo = 0; oo < 16; ++oo) {
      const int o = og * 16 + oo;
      float acc = ba[oo];
#pragma unroll
      for (int r = 0; r < 16; ++r) acc = fmaf(rbf[r], w1[o * 80 + 64 + r], acc);
      float h = acc > 0.f ? acc : 0.2f * acc;   /* leaky 0.2 */
      lg = fmaf(h, w2[o], lg);
    }
  }
  ws[WS_LOG + (size_t)k * 32768 + bn] = lg;     /* coalesced */
}

/* ---------------- K2S: softmax + att + W/W2 scatter-histograms ------------ */
__global__ __launch_bounds__(256) void k2_softmax(float* __restrict__ ws) {
  const int i = blockIdx.x;                 /* 128 blocks */
  const int xcd = i & 7, j = i >> 3;        /* j 0..15 */
  const int b = 2 * xcd + (j & 1);
  const int half = j >> 1;                  /* 0..7 */
  const int bn = (b << 11) + (half << 8) + threadIdx.x;

  float l[K_];
#pragma unroll
  for (int k = 0; k < K_; ++k) l[k] = ws[WS_LOG + (size_t)k * 32768 + bn];
  float mx = l[0];
#pragma unroll
  for (int k = 1; k < K_; ++k) mx = fmaxf(mx, l[k]);
  float den = 0.f;
#pragma unroll
  for (int k = 0; k < K_; ++k) { l[k] = __expf(l[k] - mx); den += l[k]; }
  const float inv = 1.f / den;
#pragma unroll
  for (int k = 0; k < K_; ++k) l[k] *= inv;

  float4* ap = (float4*)(ws + WS_ATT + (size_t)bn * K_);
#pragma unroll
  for (int q = 0; q < 6; ++q) {
    float4 v; v.x = l[4*q]; v.y = l[4*q+1]; v.z = l[4*q+2]; v.w = l[4*q+3];
    ap[q] = v;
  }
  const int* ip = (const int*)ws + WS_IDX + (size_t)bn * K_;
#pragma unroll
  for (int k = 0; k < K_; ++k) {
    const int mk = ip[k];
    atomicAdd(ws + WS_W  + (b << 11) + mk, l[k]);
    atomicAdd(ws + WS_W2 + (b << 11) + mk, l[k] * l[k]);
  }
}

/* ---------------- K2B: BN stats from W/W2 (coalesced sweep) --------------- */
__global__ __launch_bounds__(256) void k2b_stats(float* __restrict__ ws) {
  __shared__ float ls[128];
  const int lane = threadIdx.x & 63;
  const int wv   = __builtin_amdgcn_readfirstlane(threadIdx.x >> 6);
  if (threadIdx.x < 128) ls[threadIdx.x] = 0.f;
  __syncthreads();
  const int i = blockIdx.x;                 /* 128 blocks */
  const int xcd = i & 7, j = i >> 3;
  const int b = 2 * xcd + (j & 1);
  const int half = j >> 1;
  const float* Y = ws + WS_Y;
  float s1 = 0.f, s2 = 0.f;
#pragma unroll 1
  for (int it = 0; it < 64; ++it) {
    const int m = (b << 11) + (half << 8) + (wv << 6) + it;   /* uniform */
    const float w  = ws[WS_W + m];           /* s_load */
    const float w2 = ws[WS_W2 + m];
    const float yv = Y[(size_t)m * 256 + 128 + lane];         /* coalesced */
    s1 = fmaf(w, yv, s1);
    s2 = fmaf(w2, yv * yv, s2);
  }
  atomicAdd(&ls[lane], s1);
  atomicAdd(&ls[64 + lane], s2);
  __syncthreads();
  if (threadIdx.x < 128) atomicAdd(ws + WS_ST + threadIdx.x, ls[threadIdx.x]);
}

/* ---------------- K3: finalize BN scale/shift ----------------------------- */
__global__ void k3_bn(const float* __restrict__ gam, const float* __restrict__ bet,
                      float* __restrict__ ws) {
  const int o = threadIdx.x;   /* 64 */
  float s1 = ws[WS_ST + o], s2 = ws[WS_ST + 64 + o];
  const float cnt = (float)BNK_;
  float mean = s1 / cnt;
  float var = fmaxf(s2 / cnt - mean * mean, 0.f);
  float A = gam[o] / sqrtf(var + 1e-5f);
  ws[WS_AB + o] = A;
  ws[WS_AB + 64 + o] = bet[o] - mean * A;
}

/* ---------------- K4: BN apply + leaky + residual + mean_k + store -------- */
__global__ __launch_bounds__(256) void k4_out(float* __restrict__ out,
                                              const float* __restrict__ ws) {
  __shared__ float tile[32][65];
  const int lane = threadIdx.x & 63;
  const int wv   = __builtin_amdgcn_readfirstlane(threadIdx.x >> 6);
  const int i = blockIdx.x;                 /* 1024 blocks */
  const int xcd = i & 7, j = i >> 3;        /* j 0..127 */
  const int b = 2 * xcd + (j & 1);
  const int j2 = j >> 1;                    /* 0..63 */
  const int n0 = j2 << 5;                   /* 32-point tile */
  const float* Y = ws + WS_Y;
  const float A  = ws[WS_AB + lane];
  const float Bb = ws[WS_AB + 64 + lane];

#pragma unroll 1
  for (int pt = 0; pt < 8; ++pt) {
    const int bn = (b << 11) + n0 + (wv << 3) + pt;           /* uniform */
    const int*   ip = (const int*)ws + WS_IDX + (size_t)bn * K_;   /* s_load */
    const float* ap = ws + WS_ATT + (size_t)bn * K_;               /* s_load */
    float facc = 0.f, racc = 0.f;
#pragma unroll
    for (int k = 0; k < K_; ++k) {
      const int mk = ip[k];
      const float* row = Y + (size_t)((b << 11) + mk) * 256;
      float yv = row[128 + lane];           /* coalesced */
      float rv = row[192 + lane];           /* coalesced */
      float u = ap[k] * yv;
      float v = fmaf(u, A, Bb);
      v = v > 0.f ? v : 0.02f * v;          /* leaky 0.02 */
      facc += v;
      racc += rv;
    }
    tile[(wv << 3) + pt][lane] = (facc + 0.1f * racc) * (1.f / 24.f);
  }
  __syncthreads();
  const int o = threadIdx.x >> 2, q = threadIdx.x & 3;
  float* op = out + ((size_t)(b * 64 + o)) * 2048 + n0 + q * 8;
  float4 v0, v1;
  v0.x = tile[q*8+0][o]; v0.y = tile[q*8+1][o]; v0.z = tile[q*8+2][o]; v0.w = tile[q*8+3][o];
  v1.x = tile[q*8+4][o]; v1.y = tile[q*8+5][o]; v1.z = tile[q*8+6][o]; v1.w = tile[q*8+7][o];
  ((float4*)op)[0] = v0;
  ((float4*)op)[1] = v1;
}

extern "C" void kernel_launch(void* const* d_in, const int* in_sizes, int n_in,
                              void* d_out, int out_size, void* d_ws, size_t ws_size,
                              hipStream_t stream) {
  (void)in_sizes; (void)n_in; (void)out_size; (void)ws_size;
  const float* x    = (const float*)d_in[0];
  /* d_in[1] = idx_base (unused by reference) */
  const float* w1   = (const float*)d_in[2];
  const float* w2   = (const float*)d_in[3];
  const float* updw = (const float*)d_in[4];
  const float* bng  = (const float*)d_in[5];
  const float* bnb  = (const float*)d_in[6];
  const float* resw = (const float*)d_in[7];
  float* out = (float*)d_out;
  float* ws  = (float*)d_ws;

  k0_prep  <<<dim3(128),  dim3(256), 0, stream>>>(x, ws);
  k1_topk  <<<dim3(512),  dim3(512), 0, stream>>>(ws);
  kY       <<<dim3(256),  dim3(128), 0, stream>>>(w1, updw, resw, ws);
  k2_logits<<<dim3(3072), dim3(256), 0, stream>>>(w1, w2, ws);
  k2_softmax<<<dim3(128), dim3(256), 0, stream>>>(ws);
  k2b_stats<<<dim3(128),  dim3(256), 0, stream>>>(ws);
  k3_bn    <<<dim3(1),    dim3(64),  0, stream>>>(bng, bnb, ws);
  k4_out   <<<dim3(1024), dim3(256), 0, stream>>>(out, ws);
}

// Round 10
// 527.256 us; speedup vs baseline: 1.1356x; 1.1356x over previous
//
#include <hip/hip_runtime.h>
#include <math.h>

#define B_   16
#define C_   32
#define N_   2048
#define K_   24
#define BNK_ (B_*N_*K_)      /* 786432 */

/* ws layout (float/int32 units), ~51 MB total */
#define WS_XT   0u           /* xt[b][n][c]  : 1048576 f            */
#define WS_XXD  1048576u     /* xx fp64      : 65536 f              */
#define WS_XXF  1114112u     /* xx fp32      : 32768 f              */
#define WS_IDX  1146880u     /* idx[b][n][k] : 786432 i             */
#define WS_D2   1933312u     /* d2 [b][n][k] : 786432 f             */
#define WS_ATT  2719744u     /* att[b][n][k] : 786432 f             */
#define WS_LOG  3506176u     /* logitsT[k][bn]: 786432 f            */
#define WS_ST   4292608u     /* sum/sumsq    : 128 f                */
#define WS_AB   4292736u     /* BN A,B       : 128 f                */
#define WS_W    4292864u     /* W[m]  att-hist : 32768 f            */
#define WS_W2   4325632u     /* W2[m] att2-hist: 32768 f            */
#define WS_Y    4358400u     /* Y[m][256]: base|attn|upd|res : 8388608 f */
#define WS_L    4358400u     /* k1 lists 512*8*16*64 f (aliases Y; dead before kY) */

/* ---------------- K0: transpose x -> xt, row norms, zero stats/W ---------- */
__global__ __launch_bounds__(256) void k0_prep(const float* __restrict__ x,
                                               float* __restrict__ ws) {
  const int i = blockIdx.x;                 /* 128 blocks */
  const int xcd = i & 7, j = i >> 3;
  const int b = 2 * xcd + (j & 1);
  const int half = j >> 1;                  /* 0..7 */
  const int t = (b << 11) + (half << 8) + threadIdx.x;
  const int n = t & 2047;
  const float* xp = x + ((size_t)b * C_ * N_) + n;
  float* xt = ws + WS_XT + (size_t)t * C_;
  double s = 0.0;
#pragma unroll
  for (int c = 0; c < C_; ++c) {
    float v = xp[(size_t)c * N_];
    xt[c] = v;
    s = fma((double)v, (double)v, s);
  }
  ((double*)(ws + WS_XXD))[t] = s;
  ws[WS_XXF + t] = (float)s;
  ws[WS_W + t] = 0.f;
  ws[WS_W2 + t] = 0.f;
  if (t < 128) ws[WS_ST + t] = 0.f;
}

/* ---------------- K1a: fp32 scan of one m-eighth per wave -----------------
   Split structure (r8, 134 us) + depth-16 lists (r9-proven semantics).
   1024 blocks x 4 waves, zero LDS. Lists coalesced to ws[pg][e][j][lane]. */
__global__ __launch_bounds__(256) void k1a_scan(float* __restrict__ ws) {
  const float* xt = ws + WS_XT;
  const int lane = threadIdx.x & 63;
  const int wv   = __builtin_amdgcn_readfirstlane(threadIdx.x >> 6);
  const int i = blockIdx.x;                 /* 1024 blocks */
  const int xcd = i & 7, j = i >> 3;        /* j 0..127 */
  const int b = 2 * xcd + (j & 1);
  const int j2 = j >> 1;                    /* 0..63 */
  const int sub = j2 & 31, epair = j2 >> 5;
  const int pg = (b << 5) + sub;            /* 0..511 */
  const int e  = (epair << 2) | wv;         /* 0..7   */
  const int bn = (b << 11) + (sub << 6) + lane;

  float xn[C_];
  {
    const float4* p = (const float4*)(xt + (size_t)bn * C_);
#pragma unroll
    for (int q = 0; q < 8; ++q) {
      float4 v = p[q];
      xn[4*q] = v.x; xn[4*q+1] = v.y; xn[4*q+2] = v.z; xn[4*q+3] = v.w;
    }
  }

  float val[16];
#pragma unroll
  for (int j0 = 0; j0 < 16; ++j0) val[j0] = -3.4e38f;

  const float* mrow = xt + ((size_t)((b << 11) + (e << 8))) * C_;  /* uniform */
  const float* xxf  = ws + WS_XXF + (b << 11) + (e << 8);          /* uniform */

#pragma unroll 2
  for (int mm = 0; mm < 256; ++mm) {
    const float* r = mrow + (size_t)mm * C_;   /* wave-uniform -> s_load */
    float a0 = 0.f, a1 = 0.f, a2 = 0.f, a3 = 0.f;
#pragma unroll
    for (int c = 0; c < 8; ++c) {
      a0 = fmaf(xn[c     ], r[c     ], a0);
      a1 = fmaf(xn[c + 8 ], r[c + 8 ], a1);
      a2 = fmaf(xn[c + 16], r[c + 16], a2);
      a3 = fmaf(xn[c + 24], r[c + 24], a3);
    }
    float s = 2.f * ((a0 + a1) + (a2 + a3)) - xxf[mm];
    int sb = (__float_as_int(s) & ~2047) | ((e << 8) + mm);
    float sp = __int_as_float(sb);
#pragma unroll
    for (int j0 = 15; j0 >= 1; --j0)
      val[j0] = __builtin_amdgcn_fmed3f(val[j0 - 1], val[j0], sp);
    val[0] = fmaxf(val[0], sp);
  }

  float* Lp = ws + WS_L + (((size_t)pg * 8 + e) * 16) * 64 + lane;
#pragma unroll
  for (int j0 = 0; j0 < 16; ++j0) Lp[(size_t)j0 * 64] = val[j0];   /* coalesced */
}

/* ---------------- K1b: union select + exact fp64 re-rank ----------------- */
__global__ __launch_bounds__(64) void k1b_sel(float* __restrict__ ws) {
  const float* xt = ws + WS_XT;
  const double* xxd = (const double*)(ws + WS_XXD);
  const int lane = threadIdx.x & 63;
  const int i = blockIdx.x;                 /* 512 blocks */
  const int xcd = i & 7, j = i >> 3;        /* j 0..63 */
  const int b = 2 * xcd + (j & 1);
  const int sub = j >> 1;                   /* 0..31 */
  const int pg = (b << 5) + sub;
  const int bn = (b << 11) + (sub << 6) + lane;

  /* fp32 select of top-28 from the 128-entry union (streaming, coalesced) */
  float val[28];
#pragma unroll
  for (int j0 = 0; j0 < 28; ++j0) val[j0] = -3.4e38f;
  const float* Lp = ws + WS_L + ((size_t)pg * 8 * 16) * 64 + lane;
#pragma unroll 4
  for (int t = 0; t < 128; ++t) {
    float sp = Lp[(size_t)t * 64];
#pragma unroll
    for (int j0 = 27; j0 >= 1; --j0)
      val[j0] = __builtin_amdgcn_fmed3f(val[j0 - 1], val[j0], sp);
    val[0] = fmaxf(val[0], sp);
  }

  double xnd[C_];
  {
    const float* p = xt + (size_t)bn * C_;
#pragma unroll
    for (int c = 0; c < C_; ++c) xnd[c] = (double)p[c];
  }
  double dl[K_];
#pragma unroll
  for (int j0 = 0; j0 < K_; ++j0) dl[j0] = -1.7e308;

#pragma unroll 1
  for (int j0 = 0; j0 < 28; ++j0) {
    const int m = __float_as_int(val[j0]) & 2047;
    const float* r = xt + ((size_t)((b << 11) + m)) * C_;
    double a0 = 0.0, a1 = 0.0;
#pragma unroll
    for (int c = 0; c < 16; ++c) {
      a0 = fma((double)r[c],      xnd[c],      a0);
      a1 = fma((double)r[c + 16], xnd[c + 16], a1);
    }
    double s = 2.0 * (a0 + a1) - xxd[(b << 11) + m];
    long long bits = (__double_as_longlong(s) & 0xFFFFFFFFFFFFF800ll) | (long long)m;
    double sp = __longlong_as_double(bits);
    if (sp > dl[K_ - 1]) {     /* guarded insert */
      bool c2 = true;
#pragma unroll
      for (int jj = K_ - 1; jj >= 1; --jj) {
        bool c1 = sp > dl[jj - 1];
        dl[jj] = c1 ? dl[jj - 1] : (c2 ? sp : dl[jj]);
        c2 = c1;
      }
      if (c2) dl[0] = sp;
    }
  }

  int*   op = (int*)ws + WS_IDX + (size_t)bn * K_;
  float* dp = ws + WS_D2 + (size_t)bn * K_;
  const double xxn = xxd[bn];
#pragma unroll
  for (int rr = 0; rr < K_; ++rr) {
    long long bl = __double_as_longlong(dl[rr]);
    op[rr] = (int)(bl & 0x7FFll);
    dp[rr] = (float)(xxn - __longlong_as_double(bl & 0xFFFFFFFFFFFFF800ll));
  }
}

/* ---------------- KY: Y[m] = [xt·w1c^T | xt·w1n^T | xt·updw^T | xt·resw^T] */
__global__ __launch_bounds__(128) void kY(const float* __restrict__ w1,
                                          const float* __restrict__ updw,
                                          const float* __restrict__ resw,
                                          float* __restrict__ ws) {
  const int i = blockIdx.x;                 /* 256 blocks x 128 thr */
  const int xcd = i & 7, j = i >> 3;        /* j 0..31 */
  const int b = 2 * xcd + (j & 1);
  const int half = j >> 1;                  /* 0..15 */
  const int p = (b << 11) + (half << 7) + threadIdx.x;
  const float* xt = ws + WS_XT;

  float row[C_];
  {
    const float4* rp = (const float4*)(xt + (size_t)p * C_);
#pragma unroll
    for (int q = 0; q < 8; ++q) {
      float4 v = rp[q];
      row[4*q] = v.x; row[4*q+1] = v.y; row[4*q+2] = v.z; row[4*q+3] = v.w;
    }
  }
  float* yp = ws + WS_Y + (size_t)p * 256;
#pragma unroll 1
  for (int part = 0; part < 4; ++part) {
    const float* W = (part == 0) ? w1 : (part == 1) ? (w1 + 32)
                   : (part == 2) ? updw : resw;          /* uniform */
    const int stride = (part < 2) ? 80 : 32;
#pragma unroll 2
    for (int og = 0; og < 16; ++og) {
      float a[4] = {0.f, 0.f, 0.f, 0.f};
#pragma unroll
      for (int u = 0; u < 4; ++u) {
        const float* wr = W + (4 * og + u) * stride;     /* uniform -> s_load */
#pragma unroll
        for (int c = 0; c < C_; ++c) a[u] = fmaf(row[c], wr[c], a[u]);
      }
      float4 st; st.x = a[0]; st.y = a[1]; st.z = a[2]; st.w = a[3];
      ((float4*)(yp + part * 64))[og] = st;
    }
  }
}

/* ---------------- K2L: logits — 3 k's per wave, base row hoisted ----------
   r8 version re-read the per-point base row for every k (24x redundant,
   ~200 MB L2 traffic). Now: wave = (pg, k-triple); base loaded once into
   64 VGPRs; per k: one yp gather + 1024 FMA. 4096 waves = 4/SIMD.        */
__global__ __launch_bounds__(256) void k2_logits(const float* __restrict__ w1,
                                                 const float* __restrict__ w2,
                                                 float* __restrict__ ws) {
  const int lane = threadIdx.x & 63;
  const int wv   = __builtin_amdgcn_readfirstlane(threadIdx.x >> 6);
  const int i = blockIdx.x;                 /* 1024 blocks */
  const int xcd = i & 7, j = i >> 3;        /* j 0..127 */
  const int b = 2 * xcd + (j & 1);
  const int j2 = j >> 1;                    /* 0..63 */
  const int sub = j2 & 31;
  const int half = j2 >> 5;                 /* 0..1 */
  const int k0 = (half * 4 + wv) * 3;       /* 3 k's per wave */
  const int bn = (b << 11) + (sub << 6) + lane;
  const float* Y = ws + WS_Y;

  float ba[64];
  {
    const float4* bp = (const float4*)(Y + (size_t)bn * 256);
#pragma unroll
    for (int q = 0; q < 16; ++q) {
      float4 v = bp[q];
      ba[4*q] = v.x; ba[4*q+1] = v.y; ba[4*q+2] = v.z; ba[4*q+3] = v.w;
    }
  }
#pragma unroll 1
  for (int kk = 0; kk < 3; ++kk) {
    const int k = k0 + kk;
    const int mk  = ((const int*)ws)[WS_IDX + (size_t)bn * K_ + k];
    const float dd = ws[WS_D2 + (size_t)bn * K_ + k];
    float dist = sqrtf(fmaxf(dd, 1e-12f));
    float rbf[16];
#pragma unroll
    for (int r = 0; r < 16; ++r) {
      float t = dist - (float)r * (5.0f / 15.0f);
      float e = __expf(-10.f * t * t);
      rbf[r] = fminf(fmaxf(e, 1e-10f), 1.0f);
    }
    const float4* yp = (const float4*)(Y + (size_t)((b << 11) + mk) * 256 + 64);
    float lg = 0.f;
#pragma unroll
    for (int og = 0; og < 4; ++og) {
      float rv[16];
#pragma unroll
      for (int q = 0; q < 4; ++q) {
        float4 v = yp[og * 4 + q];
        rv[4*q] = v.x; rv[4*q+1] = v.y; rv[4*q+2] = v.z; rv[4*q+3] = v.w;
      }
#pragma unroll
      for (int oo = 0; oo < 16; ++oo) {
        const int o = og * 16 + oo;
        float acc = ba[o] + rv[oo];
#pragma unroll
        for (int r = 0; r < 16; ++r) acc = fmaf(rbf[r], w1[o * 80 + 64 + r], acc);
        float h = acc > 0.f ? acc : 0.2f * acc;   /* leaky 0.2 */
        lg = fmaf(h, w2[o], lg);
      }
    }
    ws[WS_LOG + (size_t)k * 32768 + bn] = lg;     /* coalesced */
  }
}

/* ---------------- K2S: softmax + att + W/W2 scatter-histograms ------------ */
__global__ __launch_bounds__(256) void k2_softmax(float* __restrict__ ws) {
  const int i = blockIdx.x;                 /* 128 blocks */
  const int xcd = i & 7, j = i >> 3;        /* j 0..15 */
  const int b = 2 * xcd + (j & 1);
  const int half = j >> 1;                  /* 0..7 */
  const int bn = (b << 11) + (half << 8) + threadIdx.x;

  float l[K_];
#pragma unroll
  for (int k = 0; k < K_; ++k) l[k] = ws[WS_LOG + (size_t)k * 32768 + bn];
  float mx = l[0];
#pragma unroll
  for (int k = 1; k < K_; ++k) mx = fmaxf(mx, l[k]);
  float den = 0.f;
#pragma unroll
  for (int k = 0; k < K_; ++k) { l[k] = __expf(l[k] - mx); den += l[k]; }
  const float inv = 1.f / den;
#pragma unroll
  for (int k = 0; k < K_; ++k) l[k] *= inv;

  float4* ap = (float4*)(ws + WS_ATT + (size_t)bn * K_);
#pragma unroll
  for (int q = 0; q < 6; ++q) {
    float4 v; v.x = l[4*q]; v.y = l[4*q+1]; v.z = l[4*q+2]; v.w = l[4*q+3];
    ap[q] = v;
  }
  const int* ip = (const int*)ws + WS_IDX + (size_t)bn * K_;
#pragma unroll
  for (int k = 0; k < K_; ++k) {
    const int mk = ip[k];
    atomicAdd(ws + WS_W  + (b << 11) + mk, l[k]);
    atomicAdd(ws + WS_W2 + (b << 11) + mk, l[k] * l[k]);
  }
}

/* ---------------- K2B: BN stats from W/W2 (coalesced sweep) --------------- */
__global__ __launch_bounds__(256) void k2b_stats(float* __restrict__ ws) {
  __shared__ float ls[128];
  const int lane = threadIdx.x & 63;
  const int wv   = __builtin_amdgcn_readfirstlane(threadIdx.x >> 6);
  if (threadIdx.x < 128) ls[threadIdx.x] = 0.f;
  __syncthreads();
  const int i = blockIdx.x;                 /* 128 blocks */
  const int xcd = i & 7, j = i >> 3;
  const int b = 2 * xcd + (j & 1);
  const int half = j >> 1;
  const float* Y = ws + WS_Y;
  float s1 = 0.f, s2 = 0.f;
#pragma unroll 1
  for (int it = 0; it < 64; ++it) {
    const int m = (b << 11) + (half << 8) + (wv << 6) + it;   /* uniform */
    const float w  = ws[WS_W + m];           /* s_load */
    const float w2 = ws[WS_W2 + m];
    const float yv = Y[(size_t)m * 256 + 128 + lane];         /* coalesced */
    s1 = fmaf(w, yv, s1);
    s2 = fmaf(w2, yv * yv, s2);
  }
  atomicAdd(&ls[lane], s1);
  atomicAdd(&ls[64 + lane], s2);
  __syncthreads();
  if (threadIdx.x < 128) atomicAdd(ws + WS_ST + threadIdx.x, ls[threadIdx.x]);
}

/* ---------------- K3: finalize BN scale/shift ----------------------------- */
__global__ void k3_bn(const float* __restrict__ gam, const float* __restrict__ bet,
                      float* __restrict__ ws) {
  const int o = threadIdx.x;   /* 64 */
  float s1 = ws[WS_ST + o], s2 = ws[WS_ST + 64 + o];
  const float cnt = (float)BNK_;
  float mean = s1 / cnt;
  float var = fmaxf(s2 / cnt - mean * mean, 0.f);
  float A = gam[o] / sqrtf(var + 1e-5f);
  ws[WS_AB + o] = A;
  ws[WS_AB + 64 + o] = bet[o] - mean * A;
}

/* ---------------- K4: BN apply + leaky + residual + mean_k + store -------- */
__global__ __launch_bounds__(256) void k4_out(float* __restrict__ out,
                                              const float* __restrict__ ws) {
  __shared__ float tile[32][65];
  const int lane = threadIdx.x & 63;
  const int wv   = __builtin_amdgcn_readfirstlane(threadIdx.x >> 6);
  const int i = blockIdx.x;                 /* 1024 blocks */
  const int xcd = i & 7, j = i >> 3;        /* j 0..127 */
  const int b = 2 * xcd + (j & 1);
  const int j2 = j >> 1;                    /* 0..63 */
  const int n0 = j2 << 5;                   /* 32-point tile */
  const float* Y = ws + WS_Y;
  const float A  = ws[WS_AB + lane];
  const float Bb = ws[WS_AB + 64 + lane];

#pragma unroll 1
  for (int pt = 0; pt < 8; ++pt) {
    const int bn = (b << 11) + n0 + (wv << 3) + pt;           /* uniform */
    const int*   ip = (const int*)ws + WS_IDX + (size_t)bn * K_;   /* s_load */
    const float* ap = ws + WS_ATT + (size_t)bn * K_;               /* s_load */
    float facc = 0.f, racc = 0.f;
#pragma unroll
    for (int k = 0; k < K_; ++k) {
      const int mk = ip[k];
      const float* row = Y + (size_t)((b << 11) + mk) * 256;
      float yv = row[128 + lane];           /* coalesced */
      float rv = row[192 + lane];           /* coalesced */
      float u = ap[k] * yv;
      float v = fmaf(u, A, Bb);
      v = v > 0.f ? v : 0.02f * v;          /* leaky 0.02 */
      facc += v;
      racc += rv;
    }
    tile[(wv << 3) + pt][lane] = (facc + 0.1f * racc) * (1.f / 24.f);
  }
  __syncthreads();
  const int o = threadIdx.x >> 2, q = threadIdx.x & 3;
  float* op = out + ((size_t)(b * 64 + o)) * 2048 + n0 + q * 8;
  float4 v0, v1;
  v0.x = tile[q*8+0][o]; v0.y = tile[q*8+1][o]; v0.z = tile[q*8+2][o]; v0.w = tile[q*8+3][o];
  v1.x = tile[q*8+4][o]; v1.y = tile[q*8+5][o]; v1.z = tile[q*8+6][o]; v1.w = tile[q*8+7][o];
  ((float4*)op)[0] = v0;
  ((float4*)op)[1] = v1;
}

extern "C" void kernel_launch(void* const* d_in, const int* in_sizes, int n_in,
                              void* d_out, int out_size, void* d_ws, size_t ws_size,
                              hipStream_t stream) {
  (void)in_sizes; (void)n_in; (void)out_size; (void)ws_size;
  const float* x    = (const float*)d_in[0];
  /* d_in[1] = idx_base (unused by reference) */
  const float* w1   = (const float*)d_in[2];
  const float* w2   = (const float*)d_in[3];
  const float* updw = (const float*)d_in[4];
  const float* bng  = (const float*)d_in[5];
  const float* bnb  = (const float*)d_in[6];
  const float* resw = (const float*)d_in[7];
  float* out = (float*)d_out;
  float* ws  = (float*)d_ws;

  k0_prep  <<<dim3(128),  dim3(256), 0, stream>>>(x, ws);
  k1a_scan <<<dim3(1024), dim3(256), 0, stream>>>(ws);
  k1b_sel  <<<dim3(512),  dim3(64),  0, stream>>>(ws);
  kY       <<<dim3(256),  dim3(128), 0, stream>>>(w1, updw, resw, ws);
  k2_logits<<<dim3(1024), dim3(256), 0, stream>>>(w1, w2, ws);
  k2_softmax<<<dim3(128), dim3(256), 0, stream>>>(ws);
  k2b_stats<<<dim3(128),  dim3(256), 0, stream>>>(ws);
  k3_bn    <<<dim3(1),    dim3(64),  0, stream>>>(bng, bnb, ws);
  k4_out   <<<dim3(1024), dim3(256), 0, stream>>>(out, ws);
}

// Round 11
// 433.016 us; speedup vs baseline: 1.3828x; 1.2176x over previous
//
#include <hip/hip_runtime.h>
#include <math.h>

#define B_   16
#define C_   32
#define N_   2048
#define K_   24
#define BNK_ (B_*N_*K_)      /* 786432 */

typedef float vf2 __attribute__((ext_vector_type(2)));

/* ws layout (float/int32 units), ~51 MB total */
#define WS_XT   0u           /* xt[b][n][c]  : 1048576 f            */
#define WS_XXD  1048576u     /* xx fp64      : 65536 f              */
#define WS_XXF  1114112u     /* xx fp32      : 32768 f              */
#define WS_IDX  1146880u     /* idx[b][n][k] : 786432 i             */
#define WS_D2   1933312u     /* d2 [b][n][k] : 786432 f             */
#define WS_ATT  2719744u     /* att[b][n][k] : 786432 f             */
#define WS_LOG  3506176u     /* logitsT[k][bn]: 786432 f            */
#define WS_ST   4292608u     /* sum/sumsq    : 128 f                */
#define WS_AB   4292736u     /* BN A,B       : 128 f                */
#define WS_W    4292864u     /* W[m]  att-hist : 32768 f            */
#define WS_W2   4325632u     /* W2[m] att2-hist: 32768 f            */
#define WS_Y    4358400u     /* Y[m][256]: base|attn|upd|res : 8388608 f */
#define WS_L    4358400u     /* k1 lists 512*8*16*64 f (aliases Y; dead before kY) */

/* ---------------- K0: transpose x -> xt, row norms, zero stats/W ---------- */
__global__ __launch_bounds__(256) void k0_prep(const float* __restrict__ x,
                                               float* __restrict__ ws) {
  const int i = blockIdx.x;                 /* 128 blocks */
  const int xcd = i & 7, j = i >> 3;
  const int b = 2 * xcd + (j & 1);
  const int half = j >> 1;                  /* 0..7 */
  const int t = (b << 11) + (half << 8) + threadIdx.x;
  const int n = t & 2047;
  const float* xp = x + ((size_t)b * C_ * N_) + n;
  float4* xt4 = (float4*)(ws + WS_XT + (size_t)t * C_);
  double s = 0.0;
#pragma unroll
  for (int cg = 0; cg < 8; ++cg) {
    float4 v;
    v.x = xp[(size_t)(4*cg  ) * N_];
    v.y = xp[(size_t)(4*cg+1) * N_];
    v.z = xp[(size_t)(4*cg+2) * N_];
    v.w = xp[(size_t)(4*cg+3) * N_];
    xt4[cg] = v;
    s = fma((double)v.x, (double)v.x, s);
    s = fma((double)v.y, (double)v.y, s);
    s = fma((double)v.z, (double)v.z, s);
    s = fma((double)v.w, (double)v.w, s);
  }
  ((double*)(ws + WS_XXD))[t] = s;
  ws[WS_XXF + t] = (float)s;
  ws[WS_W + t] = 0.f;
  ws[WS_W2 + t] = 0.f;
  if (t < 128) ws[WS_ST + t] = 0.f;
}

/* ---------------- K1a: fp32 scan of one m-eighth per wave -----------------
   1024 blocks x 4 waves, zero LDS. Dot restructured as float2 ext-vectors
   to trigger v_pk_fma_f32 (2 FMA/instr). Depth-16 med3 insertion lists,
   11-bit m in fp32 mantissa low bits, coalesced list writes.              */
__global__ __launch_bounds__(256) void k1a_scan(float* __restrict__ ws) {
  const float* xt = ws + WS_XT;
  const int lane = threadIdx.x & 63;
  const int wv   = __builtin_amdgcn_readfirstlane(threadIdx.x >> 6);
  const int i = blockIdx.x;                 /* 1024 blocks */
  const int xcd = i & 7, j = i >> 3;        /* j 0..127 */
  const int b = 2 * xcd + (j & 1);
  const int j2 = j >> 1;                    /* 0..63 */
  const int sub = j2 & 31, epair = j2 >> 5;
  const int pg = (b << 5) + sub;            /* 0..511 */
  const int e  = (epair << 2) | wv;         /* 0..7   */
  const int bn = (b << 11) + (sub << 6) + lane;

  vf2 xn2[16];
  {
    const float4* p = (const float4*)(xt + (size_t)bn * C_);
#pragma unroll
    for (int q = 0; q < 8; ++q) {
      float4 v = p[q];
      vf2 a, bb; a.x = v.x; a.y = v.y; bb.x = v.z; bb.y = v.w;
      xn2[2*q] = a; xn2[2*q+1] = bb;
    }
  }

  float val[16];
#pragma unroll
  for (int j0 = 0; j0 < 16; ++j0) val[j0] = -3.4e38f;

  const float* mrow = xt + ((size_t)((b << 11) + (e << 8))) * C_;  /* uniform */
  const float* xxf  = ws + WS_XXF + (b << 11) + (e << 8);          /* uniform */

#pragma unroll 2
  for (int mm = 0; mm < 256; ++mm) {
    const vf2* r2 = (const vf2*)(mrow + (size_t)mm * C_);   /* uniform -> s_load */
    vf2 a0 = {0.f, 0.f}, a1 = {0.f, 0.f}, a2 = {0.f, 0.f}, a3 = {0.f, 0.f};
#pragma unroll
    for (int c = 0; c < 4; ++c) {
      a0 += r2[c     ] * xn2[c     ];
      a1 += r2[c + 4 ] * xn2[c + 4 ];
      a2 += r2[c + 8 ] * xn2[c + 8 ];
      a3 += r2[c + 12] * xn2[c + 12];
    }
    vf2 aa = (a0 + a1) + (a2 + a3);
    float s = 2.f * (aa.x + aa.y) - xxf[mm];
    int sb = (__float_as_int(s) & ~2047) | ((e << 8) + mm);
    float sp = __int_as_float(sb);
#pragma unroll
    for (int j0 = 15; j0 >= 1; --j0)
      val[j0] = __builtin_amdgcn_fmed3f(val[j0 - 1], val[j0], sp);
    val[0] = fmaxf(val[0], sp);
  }

  float* Lp = ws + WS_L + (((size_t)pg * 8 + e) * 16) * 64 + lane;
#pragma unroll
  for (int j0 = 0; j0 < 16; ++j0) Lp[(size_t)j0 * 64] = val[j0];   /* coalesced */
}

/* ---------------- K1b: union select + exact fp64 re-rank ----------------- */
__global__ __launch_bounds__(64) void k1b_sel(float* __restrict__ ws) {
  const float* xt = ws + WS_XT;
  const double* xxd = (const double*)(ws + WS_XXD);
  const int lane = threadIdx.x & 63;
  const int i = blockIdx.x;                 /* 512 blocks */
  const int xcd = i & 7, j = i >> 3;        /* j 0..63 */
  const int b = 2 * xcd + (j & 1);
  const int sub = j >> 1;                   /* 0..31 */
  const int pg = (b << 5) + sub;
  const int bn = (b << 11) + (sub << 6) + lane;

  float val[28];
#pragma unroll
  for (int j0 = 0; j0 < 28; ++j0) val[j0] = -3.4e38f;
  const float* Lp = ws + WS_L + ((size_t)pg * 8 * 16) * 64 + lane;
#pragma unroll 4
  for (int t = 0; t < 128; ++t) {
    float sp = Lp[(size_t)t * 64];
#pragma unroll
    for (int j0 = 27; j0 >= 1; --j0)
      val[j0] = __builtin_amdgcn_fmed3f(val[j0 - 1], val[j0], sp);
    val[0] = fmaxf(val[0], sp);
  }

  double xnd[C_];
  {
    const float* p = xt + (size_t)bn * C_;
#pragma unroll
    for (int c = 0; c < C_; ++c) xnd[c] = (double)p[c];
  }
  double dl[K_];
#pragma unroll
  for (int j0 = 0; j0 < K_; ++j0) dl[j0] = -1.7e308;

#pragma unroll 1
  for (int j0 = 0; j0 < 28; ++j0) {
    const int m = __float_as_int(val[j0]) & 2047;
    const float* r = xt + ((size_t)((b << 11) + m)) * C_;
    double a0 = 0.0, a1 = 0.0;
#pragma unroll
    for (int c = 0; c < 16; ++c) {
      a0 = fma((double)r[c],      xnd[c],      a0);
      a1 = fma((double)r[c + 16], xnd[c + 16], a1);
    }
    double s = 2.0 * (a0 + a1) - xxd[(b << 11) + m];
    long long bits = (__double_as_longlong(s) & 0xFFFFFFFFFFFFF800ll) | (long long)m;
    double sp = __longlong_as_double(bits);
    if (sp > dl[K_ - 1]) {     /* guarded insert */
      bool c2 = true;
#pragma unroll
      for (int jj = K_ - 1; jj >= 1; --jj) {
        bool c1 = sp > dl[jj - 1];
        dl[jj] = c1 ? dl[jj - 1] : (c2 ? sp : dl[jj]);
        c2 = c1;
      }
      if (c2) dl[0] = sp;
    }
  }

  int*   op = (int*)ws + WS_IDX + (size_t)bn * K_;
  float* dp = ws + WS_D2 + (size_t)bn * K_;
  const double xxn = xxd[bn];
#pragma unroll
  for (int rr = 0; rr < K_; ++rr) {
    long long bl = __double_as_longlong(dl[rr]);
    op[rr] = (int)(bl & 0x7FFll);
    dp[rr] = (float)(xxn - __longlong_as_double(bl & 0xFFFFFFFFFFFFF800ll));
  }
}

/* ---------------- KY: Y[m] = [xt·w1c^T | xt·w1n^T | xt·updw^T | xt·resw^T]
   Re-gridded: 1024 blocks x 4 waves = 4096 waves (4/SIMD). Wave =
   (64-point group, 32-channel slice); slice wave-uniform -> weight s_loads. */
__global__ __launch_bounds__(256) void kY(const float* __restrict__ w1,
                                          const float* __restrict__ updw,
                                          const float* __restrict__ resw,
                                          float* __restrict__ ws) {
  const int lane = threadIdx.x & 63;
  const int wv   = __builtin_amdgcn_readfirstlane(threadIdx.x >> 6);
  const int i = blockIdx.x;                 /* 1024 blocks */
  const int xcd = i & 7, j = i >> 3;        /* j 0..127 */
  const int b = 2 * xcd + (j & 1);
  const int j2 = j >> 1;                    /* 0..63 */
  const int slot = (j2 << 2) | wv;          /* 0..255 */
  const int s  = slot & 7;                  /* slice 0..7 (uniform) */
  const int pg = slot >> 3;                 /* 0..31 */
  const int p = (b << 11) + (pg << 6) + lane;
  const float* xt = ws + WS_XT;

  float row[C_];
  {
    const float4* rp = (const float4*)(xt + (size_t)p * C_);
#pragma unroll
    for (int q = 0; q < 8; ++q) {
      float4 v = rp[q];
      row[4*q] = v.x; row[4*q+1] = v.y; row[4*q+2] = v.z; row[4*q+3] = v.w;
    }
  }
  const int part = s >> 1;                  /* 0..3 (uniform) */
  const int hch  = (s & 1) * 32;            /* first channel of slice */
  const float* W   = (part == 0) ? w1 : (part == 1) ? (w1 + 32)
                   : (part == 2) ? updw : resw;          /* uniform */
  const int stride = (part < 2) ? 80 : 32;
  float* yp = ws + WS_Y + (size_t)p * 256 + s * 32;
#pragma unroll 2
  for (int og = 0; og < 8; ++og) {
    float a[4] = {0.f, 0.f, 0.f, 0.f};
#pragma unroll
    for (int u = 0; u < 4; ++u) {
      const float* wr = W + (hch + 4 * og + u) * stride; /* uniform -> s_load */
#pragma unroll
      for (int c = 0; c < C_; ++c) a[u] = fmaf(row[c], wr[c], a[u]);
    }
    float4 st; st.x = a[0]; st.y = a[1]; st.z = a[2]; st.w = a[3];
    ((float4*)yp)[og] = st;
  }
}

/* ---------------- K2L: logits — 3 k's per wave, base row hoisted ---------- */
__global__ __launch_bounds__(256) void k2_logits(const float* __restrict__ w1,
                                                 const float* __restrict__ w2,
                                                 float* __restrict__ ws) {
  const int lane = threadIdx.x & 63;
  const int wv   = __builtin_amdgcn_readfirstlane(threadIdx.x >> 6);
  const int i = blockIdx.x;                 /* 1024 blocks */
  const int xcd = i & 7, j = i >> 3;        /* j 0..127 */
  const int b = 2 * xcd + (j & 1);
  const int j2 = j >> 1;                    /* 0..63 */
  const int sub = j2 & 31;
  const int half = j2 >> 5;                 /* 0..1 */
  const int k0 = (half * 4 + wv) * 3;       /* 3 k's per wave */
  const int bn = (b << 11) + (sub << 6) + lane;
  const float* Y = ws + WS_Y;

  float ba[64];
  {
    const float4* bp = (const float4*)(Y + (size_t)bn * 256);
#pragma unroll
    for (int q = 0; q < 16; ++q) {
      float4 v = bp[q];
      ba[4*q] = v.x; ba[4*q+1] = v.y; ba[4*q+2] = v.z; ba[4*q+3] = v.w;
    }
  }
#pragma unroll 1
  for (int kk = 0; kk < 3; ++kk) {
    const int k = k0 + kk;
    const int mk  = ((const int*)ws)[WS_IDX + (size_t)bn * K_ + k];
    const float dd = ws[WS_D2 + (size_t)bn * K_ + k];
    float dist = sqrtf(fmaxf(dd, 1e-12f));
    float rbf[16];
#pragma unroll
    for (int r = 0; r < 16; ++r) {
      float t = dist - (float)r * (5.0f / 15.0f);
      float e = __expf(-10.f * t * t);
      rbf[r] = fminf(fmaxf(e, 1e-10f), 1.0f);
    }
    const float4* yp = (const float4*)(Y + (size_t)((b << 11) + mk) * 256 + 64);
    float lg = 0.f;
#pragma unroll
    for (int og = 0; og < 4; ++og) {
      float rv[16];
#pragma unroll
      for (int q = 0; q < 4; ++q) {
        float4 v = yp[og * 4 + q];
        rv[4*q] = v.x; rv[4*q+1] = v.y; rv[4*q+2] = v.z; rv[4*q+3] = v.w;
      }
#pragma unroll
      for (int oo = 0; oo < 16; ++oo) {
        const int o = og * 16 + oo;
        float acc = ba[o] + rv[oo];
#pragma unroll
        for (int r = 0; r < 16; ++r) acc = fmaf(rbf[r], w1[o * 80 + 64 + r], acc);
        float h = acc > 0.f ? acc : 0.2f * acc;   /* leaky 0.2 */
        lg = fmaf(h, w2[o], lg);
      }
    }
    ws[WS_LOG + (size_t)k * 32768 + bn] = lg;     /* coalesced */
  }
}

/* ---------------- K2S: softmax + att + W/W2 scatter-histograms ------------ */
__global__ __launch_bounds__(256) void k2_softmax(float* __restrict__ ws) {
  const int i = blockIdx.x;                 /* 128 blocks */
  const int xcd = i & 7, j = i >> 3;        /* j 0..15 */
  const int b = 2 * xcd + (j & 1);
  const int half = j >> 1;                  /* 0..7 */
  const int bn = (b << 11) + (half << 8) + threadIdx.x;

  float l[K_];
#pragma unroll
  for (int k = 0; k < K_; ++k) l[k] = ws[WS_LOG + (size_t)k * 32768 + bn];
  float mx = l[0];
#pragma unroll
  for (int k = 1; k < K_; ++k) mx = fmaxf(mx, l[k]);
  float den = 0.f;
#pragma unroll
  for (int k = 0; k < K_; ++k) { l[k] = __expf(l[k] - mx); den += l[k]; }
  const float inv = 1.f / den;
#pragma unroll
  for (int k = 0; k < K_; ++k) l[k] *= inv;

  float4* ap = (float4*)(ws + WS_ATT + (size_t)bn * K_);
#pragma unroll
  for (int q = 0; q < 6; ++q) {
    float4 v; v.x = l[4*q]; v.y = l[4*q+1]; v.z = l[4*q+2]; v.w = l[4*q+3];
    ap[q] = v;
  }
  const int* ip = (const int*)ws + WS_IDX + (size_t)bn * K_;
#pragma unroll
  for (int k = 0; k < K_; ++k) {
    const int mk = ip[k];
    atomicAdd(ws + WS_W  + (b << 11) + mk, l[k]);
    atomicAdd(ws + WS_W2 + (b << 11) + mk, l[k] * l[k]);
  }
}

/* ---------------- K2B: BN stats from W/W2 (coalesced sweep) --------------- */
__global__ __launch_bounds__(256) void k2b_stats(float* __restrict__ ws) {
  __shared__ float ls[128];
  const int lane = threadIdx.x & 63;
  const int wv   = __builtin_amdgcn_readfirstlane(threadIdx.x >> 6);
  if (threadIdx.x < 128) ls[threadIdx.x] = 0.f;
  __syncthreads();
  const int i = blockIdx.x;                 /* 128 blocks */
  const int xcd = i & 7, j = i >> 3;
  const int b = 2 * xcd + (j & 1);
  const int half = j >> 1;
  const float* Y = ws + WS_Y;
  float s1 = 0.f, s2 = 0.f;
#pragma unroll 1
  for (int it = 0; it < 64; ++it) {
    const int m = (b << 11) + (half << 8) + (wv << 6) + it;   /* uniform */
    const float w  = ws[WS_W + m];           /* s_load */
    const float w2 = ws[WS_W2 + m];
    const float yv = Y[(size_t)m * 256 + 128 + lane];         /* coalesced */
    s1 = fmaf(w, yv, s1);
    s2 = fmaf(w2, yv * yv, s2);
  }
  atomicAdd(&ls[lane], s1);
  atomicAdd(&ls[64 + lane], s2);
  __syncthreads();
  if (threadIdx.x < 128) atomicAdd(ws + WS_ST + threadIdx.x, ls[threadIdx.x]);
}

/* ---------------- K3: finalize BN scale/shift ----------------------------- */
__global__ void k3_bn(const float* __restrict__ gam, const float* __restrict__ bet,
                      float* __restrict__ ws) {
  const int o = threadIdx.x;   /* 64 */
  float s1 = ws[WS_ST + o], s2 = ws[WS_ST + 64 + o];
  const float cnt = (float)BNK_;
  float mean = s1 / cnt;
  float var = fmaxf(s2 / cnt - mean * mean, 0.f);
  float A = gam[o] / sqrtf(var + 1e-5f);
  ws[WS_AB + o] = A;
  ws[WS_AB + 64 + o] = bet[o] - mean * A;
}

/* ---------------- K4: BN apply + leaky + residual + mean_k + store -------- */
__global__ __launch_bounds__(256) void k4_out(float* __restrict__ out,
                                              const float* __restrict__ ws) {
  __shared__ float tile[32][65];
  const int lane = threadIdx.x & 63;
  const int wv   = __builtin_amdgcn_readfirstlane(threadIdx.x >> 6);
  const int i = blockIdx.x;                 /* 1024 blocks */
  const int xcd = i & 7, j = i >> 3;        /* j 0..127 */
  const int b = 2 * xcd + (j & 1);
  const int j2 = j >> 1;                    /* 0..63 */
  const int n0 = j2 << 5;                   /* 32-point tile */
  const float* Y = ws + WS_Y;
  const float A  = ws[WS_AB + lane];
  const float Bb = ws[WS_AB + 64 + lane];

#pragma unroll 1
  for (int pt = 0; pt < 8; ++pt) {
    const int bn = (b << 11) + n0 + (wv << 3) + pt;           /* uniform */
    const int*   ip = (const int*)ws + WS_IDX + (size_t)bn * K_;   /* s_load */
    const float* ap = ws + WS_ATT + (size_t)bn * K_;               /* s_load */
    float facc = 0.f, racc = 0.f;
#pragma unroll
    for (int k = 0; k < K_; ++k) {
      const int mk = ip[k];
      const float* row = Y + (size_t)((b << 11) + mk) * 256;
      float yv = row[128 + lane];           /* coalesced */
      float rv = row[192 + lane];           /* coalesced */
      float u = ap[k] * yv;
      float v = fmaf(u, A, Bb);
      v = v > 0.f ? v : 0.02f * v;          /* leaky 0.02 */
      facc += v;
      racc += rv;
    }
    tile[(wv << 3) + pt][lane] = (facc + 0.1f * racc) * (1.f / 24.f);
  }
  __syncthreads();
  const int o = threadIdx.x >> 2, q = threadIdx.x & 3;
  float* op = out + ((size_t)(b * 64 + o)) * 2048 + n0 + q * 8;
  float4 v0, v1;
  v0.x = tile[q*8+0][o]; v0.y = tile[q*8+1][o]; v0.z = tile[q*8+2][o]; v0.w = tile[q*8+3][o];
  v1.x = tile[q*8+4][o]; v1.y = tile[q*8+5][o]; v1.z = tile[q*8+6][o]; v1.w = tile[q*8+7][o];
  ((float4*)op)[0] = v0;
  ((float4*)op)[1] = v1;
}

extern "C" void kernel_launch(void* const* d_in, const int* in_sizes, int n_in,
                              void* d_out, int out_size, void* d_ws, size_t ws_size,
                              hipStream_t stream) {
  (void)in_sizes; (void)n_in; (void)out_size; (void)ws_size;
  const float* x    = (const float*)d_in[0];
  /* d_in[1] = idx_base (unused by reference) */
  const float* w1   = (const float*)d_in[2];
  const float* w2   = (const float*)d_in[3];
  const float* updw = (const float*)d_in[4];
  const float* bng  = (const float*)d_in[5];
  const float* bnb  = (const float*)d_in[6];
  const float* resw = (const float*)d_in[7];
  float* out = (float*)d_out;
  float* ws  = (float*)d_ws;

  k0_prep  <<<dim3(128),  dim3(256), 0, stream>>>(x, ws);
  k1a_scan <<<dim3(1024), dim3(256), 0, stream>>>(ws);
  k1b_sel  <<<dim3(512),  dim3(64),  0, stream>>>(ws);
  kY       <<<dim3(1024), dim3(256), 0, stream>>>(w1, updw, resw, ws);
  k2_logits<<<dim3(1024), dim3(256), 0, stream>>>(w1, w2, ws);
  k2_softmax<<<dim3(128), dim3(256), 0, stream>>>(ws);
  k2b_stats<<<dim3(128),  dim3(256), 0, stream>>>(ws);
  k3_bn    <<<dim3(1),    dim3(64),  0, stream>>>(bng, bnb, ws);
  k4_out   <<<dim3(1024), dim3(256), 0, stream>>>(out, ws);
}